// Round 1
// baseline (16423.466 us; speedup 1.0000x reference)
//
#include <hip/hip_runtime.h>

#define FPS_THREADS 1024
#define FPS_P 20          // points per thread: 1024*20 = 20480 >= 20000
#define KNBR 32

// Reference-matching squared distance: ((dx*dx + dy*dy) + dz*dz), no FMA contraction.
__device__ __forceinline__ float sq_dist_nofma(float px, float py, float pz,
                                               float cx, float cy, float cz) {
    float dx = __fsub_rn(px, cx);
    float dy = __fsub_rn(py, cy);
    float dz = __fsub_rn(pz, cz);
    return __fadd_rn(__fadd_rn(__fmul_rn(dx, dx), __fmul_rn(dy, dy)), __fmul_rn(dz, dz));
}

// K1: AoS coords -> SoA + squared norms (norm computed exactly like jnp.sum(c**2,-1))
__global__ void prep_kernel(const float* __restrict__ coord, int N,
                            float* __restrict__ sx, float* __restrict__ sy,
                            float* __restrict__ sz, float* __restrict__ sn) {
    int i = blockIdx.x * blockDim.x + threadIdx.x;
    if (i < N) {
        float x = coord[3 * i + 0];
        float y = coord[3 * i + 1];
        float z = coord[3 * i + 2];
        sx[i] = x; sy[i] = y; sz[i] = z;
        sn[i] = __fadd_rn(__fadd_rn(__fmul_rn(x, x), __fmul_rn(y, y)), __fmul_rn(z, z));
    }
}

// K2: farthest point sampling, single block, coords + min_d in registers.
__global__ __launch_bounds__(FPS_THREADS) void fps_kernel(
    const float* __restrict__ sx, const float* __restrict__ sy,
    const float* __restrict__ sz,
    int N, int n_dst, int* __restrict__ out_idx) {
    __shared__ float sv[FPS_THREADS / 64];
    __shared__ int   si[FPS_THREADS / 64];
    __shared__ float bc[3];

    const int tid  = threadIdx.x;
    const int lane = tid & 63;
    const int wv   = tid >> 6;

    float px[FPS_P], py[FPS_P], pz[FPS_P], md[FPS_P];

    #pragma unroll
    for (int j = 0; j < FPS_P; ++j) {
        int g = tid + FPS_THREADS * j;
        bool valid = (g < N);
        // sentinel coords keep d finite and md pinned at -3e38 for invalid slots
        px[j] = valid ? sx[g] : 1e18f;
        py[j] = valid ? sy[g] : 1e18f;
        pz[j] = valid ? sz[g] : 1e18f;
    }

    float c0x = sx[0], c0y = sy[0], c0z = sz[0];
    float bv = -3e38f;
    int   bi = 0x7fffffff;
    #pragma unroll
    for (int j = 0; j < FPS_P; ++j) {
        int g = tid + FPS_THREADS * j;
        float d = sq_dist_nofma(px[j], py[j], pz[j], c0x, c0y, c0z);
        md[j] = (g < N) ? d : -3e38f;
        if (md[j] > bv) { bv = md[j]; bi = g; }   // ascending g within thread -> first-max
    }
    if (tid == 0) out_idx[0] = 0;

    for (int s = 1; s < n_dst; ++s) {
        // wave-level butterfly argmax with first-index tie-break
        float v = bv; int i = bi;
        #pragma unroll
        for (int off = 32; off; off >>= 1) {
            float v2 = __shfl_xor(v, off, 64);
            int   i2 = __shfl_xor(i, off, 64);
            if (v2 > v || (v2 == v && i2 < i)) { v = v2; i = i2; }
        }
        if (lane == 0) { sv[wv] = v; si[wv] = i; }
        __syncthreads();
        if (tid == 0) {
            float fv = sv[0]; int fi = si[0];
            for (int w = 1; w < FPS_THREADS / 64; ++w) {
                if (sv[w] > fv || (sv[w] == fv && si[w] < fi)) { fv = sv[w]; fi = si[w]; }
            }
            out_idx[s] = fi;
            bc[0] = sx[fi]; bc[1] = sy[fi]; bc[2] = sz[fi];
        }
        __syncthreads();
        float ncx = bc[0], ncy = bc[1], ncz = bc[2];

        bv = -3e38f; bi = 0x7fffffff;
        #pragma unroll
        for (int j = 0; j < FPS_P; ++j) {
            float d = sq_dist_nofma(px[j], py[j], pz[j], ncx, ncy, ncz);
            float m = fminf(md[j], d);
            md[j] = m;
            if (m > bv) { bv = m; bi = tid + FPS_THREADS * j; }
        }
        // two barriers per iteration are sufficient: sv/si and bc writes of iter s+1
        // happen only after all threads passed this iteration's barriers.
    }
}

// K3: ball query, one wave per dst. First K in-radius src indices in ascending order.
// d2 replicates reference: (dn + sn) - 2*(fma-chain inner product)  [BLAS-style matmul].
__global__ void ball_kernel(const float* __restrict__ sx, const float* __restrict__ sy,
                            const float* __restrict__ sz, const float* __restrict__ sn,
                            const int* __restrict__ idx,
                            const float* __restrict__ coord, const int* __restrict__ batch,
                            int N, int n_dst,
                            float* __restrict__ out_coord, float* __restrict__ out_esrc,
                            float* __restrict__ out_edst, float* __restrict__ out_deg,
                            float* __restrict__ out_batch,
                            int* __restrict__ nbr_i, int* __restrict__ deg_i) {
    const int d    = blockIdx.x;
    const int lane = threadIdx.x;   // block of 64
    __shared__ int nbr[KNBR];

    const int id = idx[d];
    const float cx = sx[id], cy = sy[id], cz = sz[id];
    const float dn = sn[id];
    const float RR = (float)(0.08 * 0.08);

    int cnt = 0;
    for (int base = 0; base < N && cnt < KNBR; base += 64) {
        int i = base + lane;
        bool in = false;
        if (i < N) {
            float t     = __fmul_rn(sx[i], cx);
            float inner = __fmaf_rn(sy[i], cy, t);
            inner       = __fmaf_rn(sz[i], cz, inner);
            float d2    = __fsub_rn(__fadd_rn(dn, sn[i]), __fmul_rn(2.0f, inner));
            in = (d2 <= RR);
        }
        unsigned long long m = __ballot(in);
        int pos = cnt + __popcll(m & ((1ull << lane) - 1ull));
        if (in && pos < KNBR) nbr[pos] = i;
        cnt += (int)__popcll(m);
    }
    __syncthreads();

    int deg = cnt < KNBR ? cnt : KNBR;
    if (lane < KNBR) {
        int e = (lane < deg) ? nbr[lane] : -1;
        out_esrc[d * KNBR + lane] = (float)e;
        out_edst[d * KNBR + lane] = (float)((lane < deg) ? d : -1);
        nbr_i[d * KNBR + lane] = e;
    }
    if (lane == 0) { out_deg[d] = (float)deg; deg_i[d] = deg; }
    if (lane < 3)  out_coord[d * 3 + lane] = coord[id * 3 + lane];
    if (lane == 3) out_batch[d] = (float)batch[id];
}

// K4: scatter-mean of gathered features. One block per dst, one thread per feature dim.
__global__ void agg_kernel(const float* __restrict__ feat,
                           const int* __restrict__ nbr_i, const int* __restrict__ deg_i,
                           int F, float* __restrict__ out_feat) {
    const int d = blockIdx.x;
    const int t = threadIdx.x;  // F threads
    const int deg = deg_i[d];
    float acc = 0.0f;
    for (int k = 0; k < deg; ++k) {
        int nb = nbr_i[d * KNBR + k];
        acc = __fadd_rn(acc, feat[nb * F + t]);
    }
    float den = (float)(deg > 0 ? deg : 1);
    out_feat[d * F + t] = acc / den;
}

extern "C" void kernel_launch(void* const* d_in, const int* in_sizes, int n_in,
                              void* d_out, int out_size, void* d_ws, size_t ws_size,
                              hipStream_t stream) {
    const float* coord = (const float*)d_in[0];
    const float* feat  = (const float*)d_in[1];
    const int*   batch = (const int*)d_in[2];

    const int N     = in_sizes[0] / 3;
    const int F     = in_sizes[1] / N;
    const int n_dst = N / 4;            // RATIO = 0.25

    // workspace layout
    float* sx = (float*)d_ws;
    float* sy = sx + N;
    float* sz = sy + N;
    float* sn = sz + N;
    int*   idx   = (int*)(sn + N);
    int*   nbr_i = idx + n_dst;
    int*   deg_i = nbr_i + n_dst * KNBR;

    // output layout (all written as float32), reference return order
    float* out     = (float*)d_out;
    float* o_coord = out;                         // n_dst*3
    float* o_feat  = o_coord + (size_t)n_dst * 3; // n_dst*F
    float* o_esrc  = o_feat  + (size_t)n_dst * F; // n_dst*K
    float* o_edst  = o_esrc  + (size_t)n_dst * KNBR;
    float* o_deg   = o_edst  + (size_t)n_dst * KNBR;
    float* o_batch = o_deg   + n_dst;

    prep_kernel<<<(N + 255) / 256, 256, 0, stream>>>(coord, N, sx, sy, sz, sn);
    fps_kernel<<<1, FPS_THREADS, 0, stream>>>(sx, sy, sz, N, n_dst, idx);
    ball_kernel<<<n_dst, 64, 0, stream>>>(sx, sy, sz, sn, idx, coord, batch, N, n_dst,
                                          o_coord, o_esrc, o_edst, o_deg, o_batch,
                                          nbr_i, deg_i);
    agg_kernel<<<n_dst, F, 0, stream>>>(feat, nbr_i, deg_i, F, o_feat);
}

// Round 2
// 13220.880 us; speedup vs baseline: 1.2422x; 1.2422x over previous
//
#include <hip/hip_runtime.h>

#define FPS_THREADS 512
#define FPS_P 40          // points per thread: 512*40 = 20480 >= 20000
#define KNBR 32

// Reference-matching squared distance: ((dx*dx + dy*dy) + dz*dz), no FMA contraction.
__device__ __forceinline__ float sq_dist_nofma(float px, float py, float pz,
                                               float cx, float cy, float cz) {
    float dx = __fsub_rn(px, cx);
    float dy = __fsub_rn(py, cy);
    float dz = __fsub_rn(pz, cz);
    return __fadd_rn(__fadd_rn(__fmul_rn(dx, dx), __fmul_rn(dy, dy)), __fmul_rn(dz, dz));
}

// K1: AoS coords -> SoA + squared norms (norm computed exactly like jnp.sum(c**2,-1))
__global__ void prep_kernel(const float* __restrict__ coord, int N,
                            float* __restrict__ sx, float* __restrict__ sy,
                            float* __restrict__ sz, float* __restrict__ sn) {
    int i = blockIdx.x * blockDim.x + threadIdx.x;
    if (i < N) {
        float x = coord[3 * i + 0];
        float y = coord[3 * i + 1];
        float z = coord[3 * i + 2];
        sx[i] = x; sy[i] = y; sz[i] = z;
        sn[i] = __fadd_rn(__fadd_rn(__fmul_rn(x, x), __fmul_rn(y, y)), __fmul_rn(z, z));
    }
}

// K2: farthest point sampling, single block, coords + min_d in registers.
// __launch_bounds__(512, 2): 2 waves/EU -> VGPR cap 256; arrays (160) + temps fit, no spill.
__global__ __launch_bounds__(FPS_THREADS, 2) void fps_kernel(
    const float* __restrict__ sx, const float* __restrict__ sy,
    const float* __restrict__ sz,
    int N, int n_dst, int* __restrict__ out_idx) {
    __shared__ float sv[FPS_THREADS / 64];
    __shared__ int   si[FPS_THREADS / 64];
    __shared__ float bc[3];

    const int tid  = threadIdx.x;
    const int lane = tid & 63;
    const int wv   = tid >> 6;

    float px[FPS_P], py[FPS_P], pz[FPS_P], md[FPS_P];

    #pragma unroll
    for (int j = 0; j < FPS_P; ++j) {
        int g = tid + FPS_THREADS * j;
        bool valid = (g < N);
        // sentinel coords keep d finite and md pinned at -3e38 for invalid slots
        px[j] = valid ? sx[g] : 1e18f;
        py[j] = valid ? sy[g] : 1e18f;
        pz[j] = valid ? sz[g] : 1e18f;
    }

    float c0x = sx[0], c0y = sy[0], c0z = sz[0];
    float bv = -3e38f;
    int   bi = 0x7fffffff;
    #pragma unroll
    for (int j = 0; j < FPS_P; ++j) {
        int g = tid + FPS_THREADS * j;
        float d = sq_dist_nofma(px[j], py[j], pz[j], c0x, c0y, c0z);
        md[j] = (g < N) ? d : -3e38f;
        if (md[j] > bv) { bv = md[j]; bi = g; }   // ascending g within thread -> first-max
    }
    if (tid == 0) out_idx[0] = 0;

    for (int s = 1; s < n_dst; ++s) {
        // wave-level butterfly argmax with first-index tie-break
        float v = bv; int i = bi;
        #pragma unroll
        for (int off = 32; off; off >>= 1) {
            float v2 = __shfl_xor(v, off, 64);
            int   i2 = __shfl_xor(i, off, 64);
            if (v2 > v || (v2 == v && i2 < i)) { v = v2; i = i2; }
        }
        if (lane == 0) { sv[wv] = v; si[wv] = i; }
        __syncthreads();
        if (tid == 0) {
            float fv = sv[0]; int fi = si[0];
            for (int w = 1; w < FPS_THREADS / 64; ++w) {
                if (sv[w] > fv || (sv[w] == fv && si[w] < fi)) { fv = sv[w]; fi = si[w]; }
            }
            out_idx[s] = fi;
            bc[0] = sx[fi]; bc[1] = sy[fi]; bc[2] = sz[fi];
        }
        __syncthreads();
        float ncx = bc[0], ncy = bc[1], ncz = bc[2];

        bv = -3e38f; bi = 0x7fffffff;
        #pragma unroll
        for (int j = 0; j < FPS_P; ++j) {
            float d = sq_dist_nofma(px[j], py[j], pz[j], ncx, ncy, ncz);
            float m = fminf(md[j], d);
            md[j] = m;
            if (m > bv) { bv = m; bi = tid + FPS_THREADS * j; }
        }
        // two barriers per iteration are sufficient: sv/si and bc writes of iter s+1
        // happen only after all threads passed this iteration's barriers.
    }
}

// K3: ball query, one wave per dst. First K in-radius src indices in ascending order.
// d2 replicates reference: (dn + sn) - 2*(fma-chain inner product)  [BLAS-style matmul].
__global__ void ball_kernel(const float* __restrict__ sx, const float* __restrict__ sy,
                            const float* __restrict__ sz, const float* __restrict__ sn,
                            const int* __restrict__ idx,
                            const float* __restrict__ coord, const int* __restrict__ batch,
                            int N, int n_dst,
                            float* __restrict__ out_coord, float* __restrict__ out_esrc,
                            float* __restrict__ out_edst, float* __restrict__ out_deg,
                            float* __restrict__ out_batch,
                            int* __restrict__ nbr_i, int* __restrict__ deg_i) {
    const int d    = blockIdx.x;
    const int lane = threadIdx.x;   // block of 64
    __shared__ int nbr[KNBR];

    const int id = idx[d];
    const float cx = sx[id], cy = sy[id], cz = sz[id];
    const float dn = sn[id];
    const float RR = (float)(0.08 * 0.08);

    int cnt = 0;
    for (int base = 0; base < N && cnt < KNBR; base += 64) {
        int i = base + lane;
        bool in = false;
        if (i < N) {
            float t     = __fmul_rn(sx[i], cx);
            float inner = __fmaf_rn(sy[i], cy, t);
            inner       = __fmaf_rn(sz[i], cz, inner);
            float d2    = __fsub_rn(__fadd_rn(dn, sn[i]), __fmul_rn(2.0f, inner));
            in = (d2 <= RR);
        }
        unsigned long long m = __ballot(in);
        int pos = cnt + __popcll(m & ((1ull << lane) - 1ull));
        if (in && pos < KNBR) nbr[pos] = i;
        cnt += (int)__popcll(m);
    }
    __syncthreads();

    int deg = cnt < KNBR ? cnt : KNBR;
    if (lane < KNBR) {
        int e = (lane < deg) ? nbr[lane] : -1;
        out_esrc[d * KNBR + lane] = (float)e;
        out_edst[d * KNBR + lane] = (float)((lane < deg) ? d : -1);
        nbr_i[d * KNBR + lane] = e;
    }
    if (lane == 0) { out_deg[d] = (float)deg; deg_i[d] = deg; }
    if (lane < 3)  out_coord[d * 3 + lane] = coord[id * 3 + lane];
    if (lane == 3) out_batch[d] = (float)batch[id];
}

// K4: scatter-mean of gathered features. One block per dst, one thread per feature dim.
__global__ void agg_kernel(const float* __restrict__ feat,
                           const int* __restrict__ nbr_i, const int* __restrict__ deg_i,
                           int F, float* __restrict__ out_feat) {
    const int d = blockIdx.x;
    const int t = threadIdx.x;  // F threads
    const int deg = deg_i[d];
    float acc = 0.0f;
    for (int k = 0; k < deg; ++k) {
        int nb = nbr_i[d * KNBR + k];
        acc = __fadd_rn(acc, feat[nb * F + t]);
    }
    float den = (float)(deg > 0 ? deg : 1);
    out_feat[d * F + t] = acc / den;
}

extern "C" void kernel_launch(void* const* d_in, const int* in_sizes, int n_in,
                              void* d_out, int out_size, void* d_ws, size_t ws_size,
                              hipStream_t stream) {
    const float* coord = (const float*)d_in[0];
    const float* feat  = (const float*)d_in[1];
    const int*   batch = (const int*)d_in[2];

    const int N     = in_sizes[0] / 3;
    const int F     = in_sizes[1] / N;
    const int n_dst = N / 4;            // RATIO = 0.25

    // workspace layout
    float* sx = (float*)d_ws;
    float* sy = sx + N;
    float* sz = sy + N;
    float* sn = sz + N;
    int*   idx   = (int*)(sn + N);
    int*   nbr_i = idx + n_dst;
    int*   deg_i = nbr_i + n_dst * KNBR;

    // output layout (all written as float32), reference return order
    float* out     = (float*)d_out;
    float* o_coord = out;                         // n_dst*3
    float* o_feat  = o_coord + (size_t)n_dst * 3; // n_dst*F
    float* o_esrc  = o_feat  + (size_t)n_dst * F; // n_dst*K
    float* o_edst  = o_esrc  + (size_t)n_dst * KNBR;
    float* o_deg   = o_edst  + (size_t)n_dst * KNBR;
    float* o_batch = o_deg   + n_dst;

    prep_kernel<<<(N + 255) / 256, 256, 0, stream>>>(coord, N, sx, sy, sz, sn);
    fps_kernel<<<1, FPS_THREADS, 0, stream>>>(sx, sy, sz, N, n_dst, idx);
    ball_kernel<<<n_dst, 64, 0, stream>>>(sx, sy, sz, sn, idx, coord, batch, N, n_dst,
                                          o_coord, o_esrc, o_edst, o_deg, o_batch,
                                          nbr_i, deg_i);
    agg_kernel<<<n_dst, F, 0, stream>>>(feat, nbr_i, deg_i, F, o_feat);
}